// Round 6
// baseline (210.078 us; speedup 1.0000x reference)
//
#include <hip/hip_runtime.h>
#include <stdint.h>

#define IN_F 4096
#define OUT_F 4096
#define NG 32
#define NSTEP 32   // (K/2)/64 k-steps per half (in-block split-K)

typedef __attribute__((ext_vector_type(8))) _Float16 half8;
typedef __attribute__((ext_vector_type(2))) _Float16 half2t;
typedef __attribute__((ext_vector_type(4))) float floatx4;

__device__ __forceinline__ unsigned pkh(float a, float b) {
  return __builtin_bit_cast(unsigned, __builtin_amdgcn_cvt_pkrtz(a, b));
}

// ---------------------------------------------------------------------------
// Prep: x f32 -> fp16, pair-permuted within each aligned 8-group:
// physical slots hold (x0,x4),(x1,x5),(x2,x6),(x3,x7). The in-gemm W dequant
// produces the identical permutation, so MFMA k-slots stay matched.
// ---------------------------------------------------------------------------
__global__ __launch_bounds__(256) void prep_kernel(
    const float* __restrict__ x, _Float16* __restrict__ Xh) {
  int i = blockIdx.x * 256 + threadIdx.x;
  const float4* x4 = (const float4*)x;
  float4 a = x4[2 * i];
  float4 c = x4[2 * i + 1];
  uint4 o;
  o.x = pkh(a.x, c.x);
  o.y = pkh(a.y, c.y);
  o.z = pkh(a.z, c.z);
  o.w = pkh(a.w, c.w);
  ((uint4*)Xh)[i] = o;
}

// Magic-number nibble dequant: h = fp16(1024 + (q^8)); w = (h-(1032+zp))*s.
// One int32 -> one b128 MFMA B-fragment (8 fp16, pair-permuted).
__device__ __forceinline__ half8 dequant8(unsigned v, unsigned s2u, unsigned c2u) {
  unsigned tx = v ^ 0x88888888u;
  half2t s2 = __builtin_bit_cast(half2t, s2u);
  half2t c2 = __builtin_bit_cast(half2t, c2u);
  unsigned p0 = (tx & 0x000F000Fu) | 0x64006400u;          // (n0, n4)
  unsigned p1 = ((tx >> 4) & 0x000F000Fu) | 0x64006400u;   // (n1, n5)
  unsigned p2 = ((tx >> 8) & 0x000F000Fu) | 0x64006400u;   // (n2, n6)
  unsigned p3 = ((tx >> 12) & 0x000F000Fu) | 0x64006400u;  // (n3, n7)
  half2t w0 = (__builtin_bit_cast(half2t, p0) - c2) * s2;
  half2t w1 = (__builtin_bit_cast(half2t, p1) - c2) * s2;
  half2t w2 = (__builtin_bit_cast(half2t, p2) - c2) * s2;
  half2t w3 = (__builtin_bit_cast(half2t, p3) - c2) * s2;
  uint4 o;
  o.x = __builtin_bit_cast(unsigned, w0);
  o.y = __builtin_bit_cast(unsigned, w1);
  o.z = __builtin_bit_cast(unsigned, w2);
  o.w = __builtin_bit_cast(unsigned, w3);
  return __builtin_bit_cast(half8, o);
}

// ---------------------------------------------------------------------------
// Fused W4A16 GEMM. C[m][n] = sum_k A[m][k] * W[n][k].
// R4-verified skeleton (global_load_lds A staging, XOR chunk swizzle, dbuf,
// one __syncthreads per step, in-block split-K over 8 waves) with B taken
// OUT of LDS: each lane prefetches its own 8 packed int32 per step and
// dequants directly into MFMA B-operand registers. LDS traffic halves
// (192 -> 96 KB/step); LDS size halves (64 KB).
// Grid (M/128, N/128): m-tile index varies fastest -> each of the 8 XCDs
// keeps exactly one 1 MB A-panel resident in its L2.
// ---------------------------------------------------------------------------
__global__ __launch_bounds__(512, 2) void gemm_fused(
    const _Float16* __restrict__ A, const int* __restrict__ wp,
    const float* __restrict__ wscale, const int* __restrict__ wzero,
    float* __restrict__ out, int M, int N, int K) {
  __shared__ __align__(16) _Float16 Alds[4 * 8192];  // [half*2+buf][128x64] 64 KB

  const int t = threadIdx.x;
  const int wave = t >> 6, lane = t & 63;
  const int h = wave >> 2, w2 = wave & 3;
  const int wm = (w2 >> 1) * 64, wn = (w2 & 1) * 64;
  const int r = lane & 15, quad = lane >> 4, rb = r & 7;
  const int bm = blockIdx.x * 128, bn = blockIdx.y * 128;

  floatx4 acc[4][4] = {};

  // ---- A staging (R4-verified): LDS (row, kc) holds global chunk kc^(row&7),
  // swizzle applied on the GLOBAL source address, LDS dest lane-linear. ----
  const int kc = t & 7, row0 = t >> 3, row1 = row0 + 64;
  const int gkc = kc ^ (row0 & 7);
  const _Float16* Ag = A + (size_t)bm * K;
  const _Float16* gA[4];
  gA[0] = Ag + (size_t)row0 * K + gkc * 8;          // half 0
  gA[1] = Ag + (size_t)row1 * K + gkc * 8;
  gA[2] = gA[0] + 2048;                             // half 1
  gA[3] = gA[1] + 2048;

  auto STAGE_A = [&](int i, int buf) {
#pragma unroll
    for (int j = 0; j < 4; ++j) {
      const _Float16* src = gA[j] + i * 64;
      int dst = ((j >> 1) * 2 + buf) * 8192 + (t + 512 * (j & 1)) * 8;
      __builtin_amdgcn_global_load_lds(
          (const __attribute__((address_space(1))) void*)src,
          (__attribute__((address_space(3))) void*)(&Alds[dst]), 16, 0, 0);
    }
  };

  // ---- B: per-lane direct dequant. Lane needs int32 at
  // (row = bn+wn+ni*16+r, chunk = h*256 + i*8 + ks*4 + quad). ----
  unsigned boff[4];   // byte offsets into wp
  unsigned goff[4];   // element offsets into wscale/wzero
#pragma unroll
  for (int ni = 0; ni < 4; ++ni) {
    unsigned nrow = (unsigned)(bn + wn + ni * 16 + r);
    boff[ni] = (nrow * (IN_F / 8) + (unsigned)(h * 256 + quad)) * 4u;
    goff[ni] = nrow * NG + (unsigned)(h * 16);
  }
  const char* wp8 = (const char*)wp;

  unsigned bq[8], bqn[8];          // packed W: [ni*2+ks], cur / next step
  unsigned s2[4], c2[4];           // packed fp16x2 scale consts, current step
  float sfn[4];                    // scale/zero prefetched for next step
  int zfn[4];

  auto LOADB = [&](int i, unsigned* dst) {
#pragma unroll
    for (int ni = 0; ni < 4; ++ni)
#pragma unroll
      for (int ks = 0; ks < 2; ++ks)
        dst[ni * 2 + ks] =
            *(const unsigned*)(wp8 + boff[ni] + (unsigned)(i * 32 + ks * 16));
  };
  auto LOADS = [&](int i) {
    int g = i >> 1;
#pragma unroll
    for (int ni = 0; ni < 4; ++ni) {
      sfn[ni] = wscale[goff[ni] + g];
      zfn[ni] = wzero[goff[ni] + g];
    }
  };
  auto PACKS = [&]() {
#pragma unroll
    for (int ni = 0; ni < 4; ++ni) {
      _Float16 sh = (_Float16)sfn[ni];
      _Float16 ch = (_Float16)(float)(1032 + zfn[ni]);  // exact in fp16
      s2[ni] = (unsigned)__builtin_bit_cast(unsigned short, sh) * 0x10001u;
      c2[ni] = (unsigned)__builtin_bit_cast(unsigned short, ch) * 0x10001u;
    }
  };

  // ---- prologue: stage step 0, regs for step 0 + prefetch step 1 ----
  STAGE_A(0, 0);
  LOADB(0, bq);
  LOADS(0);
  PACKS();            // scales for step 0
  LOADB(1, bqn);
  LOADS(1);           // scale values for step 1 (packed at end of step 0)
  __syncthreads();

  int cur = 0;
  for (int i = 0; i < NSTEP; ++i) {
    const int nxt = cur ^ 1;
    if (i + 1 < NSTEP) STAGE_A(i + 1, nxt);   // DMA hides under MFMA phase

    const _Float16* Ab = &Alds[(h * 2 + cur) * 8192];
#pragma unroll
    for (int ks = 0; ks < 2; ++ks) {
      half8 af[4], bf[4];
#pragma unroll
      for (int mi = 0; mi < 4; ++mi) {
        int R = wm + mi * 16 + r;             // R&7 == rb
        af[mi] = *(const half8*)&Ab[R * 64 + (((ks * 4 + quad) ^ rb) << 3)];
      }
#pragma unroll
      for (int ni = 0; ni < 4; ++ni)
        bf[ni] = dequant8(bq[ni * 2 + ks], s2[ni], c2[ni]);
#pragma unroll
      for (int mi = 0; mi < 4; ++mi)
#pragma unroll
        for (int ni = 0; ni < 4; ++ni)
          acc[mi][ni] = __builtin_amdgcn_mfma_f32_16x16x32_f16(
              af[mi], bf[ni], acc[mi][ni], 0, 0, 0);
    }

    if (i + 1 < NSTEP) {
      // Promote prefetched regs (had the whole MFMA phase to land), then
      // prefetch for step i+2.
#pragma unroll
      for (int j2 = 0; j2 < 8; ++j2) bq[j2] = bqn[j2];
      PACKS();                                // packs step i+1's scales
      if (i + 2 < NSTEP) {
        LOADB(i + 2, bqn);
        LOADS(i + 2);
      }
    }
    __syncthreads();   // A(i+1) DMA drained; buf cur free for overwrite
    cur = nxt;
  }

  // ---- in-block split-K reduction (reuse A LDS region) ----
  floatx4* red = (floatx4*)Alds;
  if (h == 1) {
#pragma unroll
    for (int mi = 0; mi < 4; ++mi)
#pragma unroll
      for (int ni = 0; ni < 4; ++ni)
        red[(mi * 4 + ni) * 256 + w2 * 64 + lane] = acc[mi][ni];
  }
  __syncthreads();
  if (h == 0) {
#pragma unroll
    for (int mi = 0; mi < 4; ++mi) {
#pragma unroll
      for (int ni = 0; ni < 4; ++ni) {
        acc[mi][ni] += red[(mi * 4 + ni) * 256 + w2 * 64 + lane];
#pragma unroll
        for (int i = 0; i < 4; ++i) {
          int grow = bm + wm + mi * 16 + quad * 4 + i;
          int gcol = bn + wn + ni * 16 + r;
          out[(size_t)grow * N + gcol] = acc[mi][ni][i];
        }
      }
    }
  }
}

extern "C" void kernel_launch(void* const* d_in, const int* in_sizes, int n_in,
                              void* d_out, int out_size, void* d_ws, size_t ws_size,
                              hipStream_t stream) {
  const float* x = (const float*)d_in[0];
  const int* wp = (const int*)d_in[1];
  const float* wscale = (const float*)d_in[2];
  const int* wzero = (const int*)d_in[3];
  float* out = (float*)d_out;

  int M = in_sizes[0] / IN_F;  // 1024

  // Workspace: Xh (fp16 M*K = 8.39 MB) only.
  _Float16* Xh = (_Float16*)d_ws;

  int nxb = (M * IN_F / 8) / 256;   // 2048 blocks
  prep_kernel<<<nxb, 256, 0, stream>>>(x, Xh);

  dim3 grid(M / 128, OUT_F / 128);  // (8, 32): m fastest -> 1 A-panel per XCD
  gemm_fused<<<grid, 512, 0, stream>>>(Xh, wp, wscale, wzero, out, M, OUT_F, IN_F);
}

// Round 7
// 128.136 us; speedup vs baseline: 1.6395x; 1.6395x over previous
//
#include <hip/hip_runtime.h>
#include <stdint.h>

#define IN_F 4096
#define OUT_F 4096
#define NG 32
#define NSTEP 32   // (K/2)/64 k-steps per half (in-block split-K)

typedef __attribute__((ext_vector_type(8))) _Float16 half8;
typedef __attribute__((ext_vector_type(2))) _Float16 half2t;
typedef __attribute__((ext_vector_type(4))) float floatx4;

__device__ __forceinline__ unsigned pkh(float a, float b) {
  return __builtin_bit_cast(unsigned, __builtin_amdgcn_cvt_pkrtz(a, b));
}

// ---------------------------------------------------------------------------
// Prep (R4-verified): x f32 -> fp16 pair-permuted; scale/zero -> fp16x2 table.
// ---------------------------------------------------------------------------
__global__ __launch_bounds__(256) void prep_kernel(
    const float* __restrict__ x, _Float16* __restrict__ Xh,
    const float* __restrict__ wscale, const int* __restrict__ wzero,
    uint2* __restrict__ SZ, int nxb) {
  int b = blockIdx.x;
  if (b < nxb) {
    int i = b * 256 + threadIdx.x;
    const float4* x4 = (const float4*)x;
    float4 a = x4[2 * i];
    float4 c = x4[2 * i + 1];
    uint4 o;
    o.x = pkh(a.x, c.x);   // (x0,x4)
    o.y = pkh(a.y, c.y);
    o.z = pkh(a.z, c.z);
    o.w = pkh(a.w, c.w);
    ((uint4*)Xh)[i] = o;
  } else {
    int i = (b - nxb) * 256 + threadIdx.x;
    float s = wscale[i];
    int zp = wzero[i];
    _Float16 sh = (_Float16)s;
    _Float16 ch = (_Float16)(float)(1032 + zp);  // exact in fp16
    unsigned s2 = (unsigned)__builtin_bit_cast(unsigned short, sh) * 0x10001u;
    unsigned c2 = (unsigned)__builtin_bit_cast(unsigned short, ch) * 0x10001u;
    SZ[i] = make_uint2(s2, c2);
  }
}

__device__ __forceinline__ uint4 dequant8(unsigned v, uint2 szv) {
  unsigned tx = v ^ 0x88888888u;
  half2t s2 = __builtin_bit_cast(half2t, szv.x);
  half2t c2 = __builtin_bit_cast(half2t, szv.y);
  unsigned p0 = (tx & 0x000F000Fu) | 0x64006400u;          // (n0, n4)
  unsigned p1 = ((tx >> 4) & 0x000F000Fu) | 0x64006400u;   // (n1, n5)
  unsigned p2 = ((tx >> 8) & 0x000F000Fu) | 0x64006400u;   // (n2, n6)
  unsigned p3 = ((tx >> 12) & 0x000F000Fu) | 0x64006400u;  // (n3, n7)
  half2t w0 = (__builtin_bit_cast(half2t, p0) - c2) * s2;
  half2t w1 = (__builtin_bit_cast(half2t, p1) - c2) * s2;
  half2t w2 = (__builtin_bit_cast(half2t, p2) - c2) * s2;
  half2t w3 = (__builtin_bit_cast(half2t, p3) - c2) * s2;
  uint4 o;
  o.x = __builtin_bit_cast(unsigned, w0);
  o.y = __builtin_bit_cast(unsigned, w1);
  o.z = __builtin_bit_cast(unsigned, w2);
  o.w = __builtin_bit_cast(unsigned, w3);
  return o;
}

// ---------------------------------------------------------------------------
// Fused W4A16 GEMM = R4 skeleton + 3-deep A pipeline + counted vmcnt barriers.
// 8 waves, in-block split-K (waves 0-3: k<2048, waves 4-7: k>=2048),
// wave tile 64x64 (acc[4][4], 32 MFMA/step), XOR chunk swizzle (R4-verified).
// A: 3 LDS stages (96 KB) via global_load_lds; STAGE_A(i+2) issued at step i,
//    deadline end of step i+1 -> a full step of latency slack.
// B: 2 LDS buffers (64 KB), dequant in-register from coalesced loads; two
//    NAMED reg sets (vA/vB) alternate via unroll-by-2 (no promotion copies).
// Barrier: s_waitcnt vmcnt(4) lgkmcnt(0); s_barrier; sched_barrier(0).
//   The 4 newest vmem ops are stage(i+2)'s 4 global_load_lds (pinned by a
//   compiler memory fence after all B loads) => vmcnt(4) proves stage(i+1)
//   retired, independent of how B loads got scheduled/merged.
// LDS total 160 KB (exactly the CU limit), 1 block/CU.
// ---------------------------------------------------------------------------
__global__ __launch_bounds__(512, 2) void gemm_fused(
    const _Float16* __restrict__ A, const int* __restrict__ wp,
    const uint2* __restrict__ SZ, float* __restrict__ out,
    int M, int N, int K) {
  __shared__ __align__(16) _Float16 Alds[6 * 8192];  // [stage][half][128x64] 96 KB
  __shared__ __align__(16) _Float16 Blds[4 * 8192];  // [buf][half]          64 KB

  const int t = threadIdx.x;
  const int wave = t >> 6, lane = t & 63;
  const int h = wave >> 2, w2 = wave & 3;
  const int wm = (w2 >> 1) * 64, wn = (w2 & 1) * 64;
  const int r = lane & 15, quad = lane >> 4, rb = r & 7;
  const int bm = blockIdx.y * 128, bn = blockIdx.x * 128;

  floatx4 acc[4][4] = {};

  // ---- A staging (R4): LDS (row,kc) holds global chunk kc^(row&7); swizzle
  // on the GLOBAL source address, LDS dest lane-linear. ----
  const int kc = t & 7, row0 = t >> 3, row1 = row0 + 64;
  const int gkc = kc ^ (row0 & 7);
  const _Float16* Ag = A + (size_t)bm * K;
  const _Float16* gA[4];
  gA[0] = Ag + (size_t)row0 * K + gkc * 8;          // half 0
  gA[1] = Ag + (size_t)row1 * K + gkc * 8;
  gA[2] = gA[0] + 2048;                             // half 1
  gA[3] = gA[1] + 2048;

#define STAGE_A(i, st)                                                        \
  {                                                                           \
    _Pragma("unroll") for (int j = 0; j < 4; ++j) {                           \
      const _Float16* src = gA[j] + (i) * 64;                                 \
      int dst = ((st) * 2 + (j >> 1)) * 8192 + (t + 512 * (j & 1)) * 8;       \
      __builtin_amdgcn_global_load_lds(                                       \
          (const __attribute__((address_space(1))) void*)src,                 \
          (__attribute__((address_space(3))) void*)(&Alds[dst]), 16, 0, 0);   \
    }                                                                         \
  }

  // ---- B staging (R4): coalesced per-thread loads, swizzled ds_write. ----
  const int brow0 = t >> 3, kc8 = t & 7;
  const int* gB0 = wp + (size_t)(bn + brow0) * (IN_F / 8) + kc8;
  const int* gB1 = wp + (size_t)(bn + brow0 + 64) * (IN_F / 8) + kc8;
  const uint2* gS0 = SZ + (size_t)(bn + brow0) * NG;
  const uint2* gS1 = SZ + (size_t)(bn + brow0 + 64) * NG;
  const int bslot0 = brow0 * 64 + ((kc8 ^ (brow0 & 7)) << 3);
  const int bslot1 = (brow0 + 64) * 64 + ((kc8 ^ (brow0 & 7)) << 3);

#define LOADV(i, v, s)                                                        \
  {                                                                           \
    v[0] = (unsigned)gB0[(i) * 8];                                            \
    v[1] = (unsigned)gB1[(i) * 8];                                            \
    v[2] = (unsigned)gB0[(i) * 8 + 256];                                      \
    v[3] = (unsigned)gB1[(i) * 8 + 256];                                      \
    int g0 = (i) >> 1;                                                        \
    s[0] = gS0[g0];                                                           \
    s[1] = gS1[g0];                                                           \
    s[2] = gS0[g0 + 16];                                                      \
    s[3] = gS1[g0 + 16];                                                      \
  }

#define WRITE_B(v, s, dstbuf)                                                 \
  {                                                                           \
    _Pragma("unroll") for (int j = 0; j < 4; ++j) {                           \
      int ofs = ((dstbuf) * 2 + (j >> 1)) * 8192 + ((j & 1) ? bslot1 : bslot0); \
      *(uint4*)&Blds[ofs] = dequant8(v[j], s[j]);                             \
    }                                                                         \
  }

  unsigned vA[4], vB[4];
  uint2 sA[4], sB[4];
  int ra = 0, rw = 2;   // A stage read / write indices (mod 3)

  // ---- prologue ----
  LOADV(0, vB, sB);
  WRITE_B(vB, sB, 0);                 // B(0) -> buf0 (compiler waits its loads)
  LOADV(1, vA, sA);                   // regs for step 0's WRITE_B(1)
  asm volatile("" ::: "memory");      // pin: all B loads before the stages
  STAGE_A(0, 0);
  STAGE_A(1, 1);                      // newest 4 vmem = stage(1)
  asm volatile("s_waitcnt vmcnt(4) lgkmcnt(0)" ::: "memory");  // A(0), B(0) ready
  __builtin_amdgcn_s_barrier();
  __builtin_amdgcn_sched_barrier(0);

#define STEP(i, p, vC, sC, vL, sL)                                            \
  {                                                                           \
    if ((i) + 1 < NSTEP) WRITE_B(vC, sC, (p) ^ 1);                            \
    if ((i) + 2 < NSTEP) LOADV((i) + 2, vL, sL);                              \
    asm volatile("" ::: "memory");    /* pin B loads before stage DMAs */     \
    if ((i) + 2 < NSTEP) STAGE_A((i) + 2, rw);                                \
    const _Float16* Ab = &Alds[(ra * 2 + h) * 8192];                          \
    const _Float16* Bb = &Blds[((p) * 2 + h) * 8192];                         \
    _Pragma("unroll") for (int ks = 0; ks < 2; ++ks) {                        \
      half8 af[4], bf[4];                                                     \
      _Pragma("unroll") for (int mi = 0; mi < 4; ++mi) {                      \
        int R = wm + mi * 16 + r;                                             \
        af[mi] = *(const half8*)&Ab[R * 64 + (((ks * 4 + quad) ^ rb) << 3)];  \
      }                                                                       \
      _Pragma("unroll") for (int ni = 0; ni < 4; ++ni) {                      \
        int R = wn + ni * 16 + r;                                             \
        bf[ni] = *(const half8*)&Bb[R * 64 + (((ks * 4 + quad) ^ rb) << 3)];  \
      }                                                                       \
      _Pragma("unroll") for (int mi = 0; mi < 4; ++mi)                        \
        _Pragma("unroll") for (int ni = 0; ni < 4; ++ni)                      \
          acc[mi][ni] = __builtin_amdgcn_mfma_f32_16x16x32_f16(               \
              af[mi], bf[ni], acc[mi][ni], 0, 0, 0);                          \
    }                                                                         \
    if ((i) + 2 < NSTEP)                                                      \
      asm volatile("s_waitcnt vmcnt(4) lgkmcnt(0)" ::: "memory");             \
    else                                                                      \
      asm volatile("s_waitcnt vmcnt(0) lgkmcnt(0)" ::: "memory");             \
    __builtin_amdgcn_s_barrier();                                             \
    __builtin_amdgcn_sched_barrier(0);                                        \
    ra = (ra + 1 == 3) ? 0 : ra + 1;                                          \
    rw = (rw + 1 == 3) ? 0 : rw + 1;                                          \
  }

  for (int i = 0; i < NSTEP; i += 2) {
    STEP(i, 0, vA, sA, vB, sB);       // even: read buf0, write buf1
    STEP(i + 1, 1, vB, sB, vA, sA);   // odd:  read buf1, write buf0
  }

  // ---- in-block split-K reduction (reuse A LDS region, 64 KB needed) ----
  floatx4* red = (floatx4*)Alds;
  if (h == 1) {
#pragma unroll
    for (int mi = 0; mi < 4; ++mi)
#pragma unroll
      for (int ni = 0; ni < 4; ++ni)
        red[(mi * 4 + ni) * 256 + w2 * 64 + lane] = acc[mi][ni];
  }
  __syncthreads();
  if (h == 0) {
#pragma unroll
    for (int mi = 0; mi < 4; ++mi) {
#pragma unroll
      for (int ni = 0; ni < 4; ++ni) {
        acc[mi][ni] += red[(mi * 4 + ni) * 256 + w2 * 64 + lane];
#pragma unroll
        for (int i = 0; i < 4; ++i) {
          int grow = bm + wm + mi * 16 + quad * 4 + i;
          int gcol = bn + wn + ni * 16 + r;
          out[(size_t)grow * N + gcol] = acc[mi][ni][i];
        }
      }
    }
  }
}

extern "C" void kernel_launch(void* const* d_in, const int* in_sizes, int n_in,
                              void* d_out, int out_size, void* d_ws, size_t ws_size,
                              hipStream_t stream) {
  const float* x = (const float*)d_in[0];
  const int* wp = (const int*)d_in[1];
  const float* wscale = (const float*)d_in[2];
  const int* wzero = (const int*)d_in[3];
  float* out = (float*)d_out;

  int M = in_sizes[0] / IN_F;  // 1024

  // Workspace: Xh (fp16 M*K = 8.39 MB) | SZ (1 MB)
  _Float16* Xh = (_Float16*)d_ws;
  uint2* SZ = (uint2*)((char*)d_ws + (size_t)M * IN_F * 2);

  int nxb = (M * IN_F / 8) / 256;       // 2048 blocks for x-convert
  int nzb = (OUT_F * NG) / 256;         // 512 blocks for scale/zero table
  prep_kernel<<<nxb + nzb, 256, 0, stream>>>(x, Xh, wscale, wzero, SZ, nxb);

  dim3 grid(OUT_F / 128, M / 128);      // (32, 8) = 256 blocks = 1/CU
  gemm_fused<<<grid, 512, 0, stream>>>(Xh, wp, SZ, out, M, OUT_F, IN_F);
}

// Round 8
// 125.779 us; speedup vs baseline: 1.6702x; 1.0187x over previous
//
#include <hip/hip_runtime.h>
#include <stdint.h>

#define IN_F 4096
#define OUT_F 4096
#define NG 32
#define NSTEP 32   // (K/2)/64 k-steps per half (in-block split-K)

typedef __attribute__((ext_vector_type(8))) _Float16 half8;
typedef __attribute__((ext_vector_type(2))) _Float16 half2t;
typedef __attribute__((ext_vector_type(4))) float floatx4;

__device__ __forceinline__ unsigned pkh(float a, float b) {
  return __builtin_bit_cast(unsigned, __builtin_amdgcn_cvt_pkrtz(a, b));
}

// ---------------------------------------------------------------------------
// Prep (R4-verified): x f32 -> fp16 pair-permuted; scale/zero -> fp16x2 table.
// ---------------------------------------------------------------------------
__global__ __launch_bounds__(256) void prep_kernel(
    const float* __restrict__ x, _Float16* __restrict__ Xh,
    const float* __restrict__ wscale, const int* __restrict__ wzero,
    uint2* __restrict__ SZ, int nxb) {
  int b = blockIdx.x;
  if (b < nxb) {
    int i = b * 256 + threadIdx.x;
    const float4* x4 = (const float4*)x;
    float4 a = x4[2 * i];
    float4 c = x4[2 * i + 1];
    uint4 o;
    o.x = pkh(a.x, c.x);   // (x0,x4)
    o.y = pkh(a.y, c.y);
    o.z = pkh(a.z, c.z);
    o.w = pkh(a.w, c.w);
    ((uint4*)Xh)[i] = o;
  } else {
    int i = (b - nxb) * 256 + threadIdx.x;
    float s = wscale[i];
    int zp = wzero[i];
    _Float16 sh = (_Float16)s;
    _Float16 ch = (_Float16)(float)(1032 + zp);  // exact in fp16
    unsigned s2 = (unsigned)__builtin_bit_cast(unsigned short, sh) * 0x10001u;
    unsigned c2 = (unsigned)__builtin_bit_cast(unsigned short, ch) * 0x10001u;
    SZ[i] = make_uint2(s2, c2);
  }
}

__device__ __forceinline__ uint4 dequant8(unsigned v, uint2 szv) {
  unsigned tx = v ^ 0x88888888u;
  half2t s2 = __builtin_bit_cast(half2t, szv.x);
  half2t c2 = __builtin_bit_cast(half2t, szv.y);
  unsigned p0 = (tx & 0x000F000Fu) | 0x64006400u;          // (n0, n4)
  unsigned p1 = ((tx >> 4) & 0x000F000Fu) | 0x64006400u;   // (n1, n5)
  unsigned p2 = ((tx >> 8) & 0x000F000Fu) | 0x64006400u;   // (n2, n6)
  unsigned p3 = ((tx >> 12) & 0x000F000Fu) | 0x64006400u;  // (n3, n7)
  half2t w0 = (__builtin_bit_cast(half2t, p0) - c2) * s2;
  half2t w1 = (__builtin_bit_cast(half2t, p1) - c2) * s2;
  half2t w2 = (__builtin_bit_cast(half2t, p2) - c2) * s2;
  half2t w3 = (__builtin_bit_cast(half2t, p3) - c2) * s2;
  uint4 o;
  o.x = __builtin_bit_cast(unsigned, w0);
  o.y = __builtin_bit_cast(unsigned, w1);
  o.z = __builtin_bit_cast(unsigned, w2);
  o.w = __builtin_bit_cast(unsigned, w3);
  return o;
}

// ---------------------------------------------------------------------------
// Fused W4A16 GEMM: R7 skeleton with CORRECT counted vmcnt.
// Per step the vmem instruction count is deterministic (no other vmem in the
// loop, fences pin ordering):
//   even step: 4 B-dword + 4 SZ-dwordx2 + 4 global_load_lds = 12 -> vmcnt(12)
//   odd  step: 4 B-dword + 4 global_load_lds               =  8 -> vmcnt(8)
// => stage(i+1), issued at step i-1, is OLDER than the kept window: proven
// complete at the barrier. This step's B loads + stage(i+2) stay in flight
// with a full step of slack. Never drain vmcnt to 0 in the main loop (T4).
// Scale loads only on even steps (one pair ahead: g = i/2+1, used by the two
// WRITE_Bs of steps i+1, i+2).
// ---------------------------------------------------------------------------
__global__ __launch_bounds__(512, 2) void gemm_fused(
    const _Float16* __restrict__ A, const int* __restrict__ wp,
    const uint2* __restrict__ SZ, float* __restrict__ out,
    int M, int N, int K) {
  __shared__ __align__(16) _Float16 Alds[6 * 8192];  // [stage][half] 96 KB
  __shared__ __align__(16) _Float16 Blds[4 * 8192];  // [buf][half]   64 KB

  const int t = threadIdx.x;
  const int wave = t >> 6, lane = t & 63;
  const int h = wave >> 2, w2 = wave & 3;
  const int wm = (w2 >> 1) * 64, wn = (w2 & 1) * 64;
  const int r = lane & 15, quad = lane >> 4, rb = r & 7;
  const int bm = blockIdx.y * 128, bn = blockIdx.x * 128;

  floatx4 acc[4][4] = {};

  // ---- A staging (R4): LDS (row,kc) holds global chunk kc^(row&7); swizzle
  // on the GLOBAL source address, LDS dest lane-linear. ----
  const int kc = t & 7, row0 = t >> 3, row1 = row0 + 64;
  const int gkc = kc ^ (row0 & 7);
  const _Float16* Ag = A + (size_t)bm * K;
  const _Float16* gA[4];
  gA[0] = Ag + (size_t)row0 * K + gkc * 8;          // half 0
  gA[1] = Ag + (size_t)row1 * K + gkc * 8;
  gA[2] = gA[0] + 2048;                             // half 1
  gA[3] = gA[1] + 2048;

#define STAGE_A(i, st)                                                        \
  {                                                                           \
    _Pragma("unroll") for (int j = 0; j < 4; ++j) {                           \
      const _Float16* src = gA[j] + (i) * 64;                                 \
      int dst = ((st) * 2 + (j >> 1)) * 8192 + (t + 512 * (j & 1)) * 8;       \
      __builtin_amdgcn_global_load_lds(                                       \
          (const __attribute__((address_space(1))) void*)src,                 \
          (__attribute__((address_space(3))) void*)(&Alds[dst]), 16, 0, 0);   \
    }                                                                         \
  }

  // ---- B staging (R4): coalesced per-thread loads, swizzled ds_write. ----
  const int brow0 = t >> 3, kc8 = t & 7;
  const int* gB0 = wp + (size_t)(bn + brow0) * (IN_F / 8) + kc8;
  const int* gB1 = wp + (size_t)(bn + brow0 + 64) * (IN_F / 8) + kc8;
  const uint2* gS0 = SZ + (size_t)(bn + brow0) * NG;
  const uint2* gS1 = SZ + (size_t)(bn + brow0 + 64) * NG;
  const int bslot0 = brow0 * 64 + ((kc8 ^ (brow0 & 7)) << 3);
  const int bslot1 = (brow0 + 64) * 64 + ((kc8 ^ (brow0 & 7)) << 3);

#define LOADV_B(i, v)                                                         \
  {                                                                           \
    v[0] = (unsigned)gB0[(i) * 8];                                            \
    v[1] = (unsigned)gB1[(i) * 8];                                            \
    v[2] = (unsigned)gB0[(i) * 8 + 256];                                      \
    v[3] = (unsigned)gB1[(i) * 8 + 256];                                      \
  }

#define LOADV_S(g)                                                            \
  {                                                                           \
    sCur[0] = gS0[(g)];                                                       \
    sCur[1] = gS1[(g)];                                                       \
    sCur[2] = gS0[(g) + 16];                                                  \
    sCur[3] = gS1[(g) + 16];                                                  \
  }

#define WRITE_B(v, dstbuf)                                                    \
  {                                                                           \
    _Pragma("unroll") for (int j = 0; j < 4; ++j) {                           \
      int ofs = ((dstbuf) * 2 + (j >> 1)) * 8192 + ((j & 1) ? bslot1 : bslot0); \
      *(uint4*)&Blds[ofs] = dequant8(v[j], sCur[j]);                          \
    }                                                                         \
  }

  unsigned vA[4], vB[4];
  uint2 sCur[4];
  int ra = 0, rw = 2;   // A stage read / write indices (mod 3)

  // ---- prologue ----
  LOADV_B(0, vB);
  LOADV_S(0);                          // g=0 serves B0..B3? no: B0,B1 (g=0)
  WRITE_B(vB, 0);                      // B(0) -> buf0
  LOADV_B(1, vA);                      // regs for step 0's WRITE_B(B1)
  asm volatile("" ::: "memory");       // pin B loads before the stage DMAs
  STAGE_A(0, 0);
  STAGE_A(1, 1);                       // newest 4 vmem = stage(1)
  asm volatile("s_waitcnt vmcnt(4) lgkmcnt(0)" ::: "memory");  // A0,B0 ready
  __builtin_amdgcn_s_barrier();
  __builtin_amdgcn_sched_barrier(0);

  // STEP: even steps load scales for the NEXT pair (g = i/2+1) AFTER WRITE_B
  // consumed the current ones (program order protects the old values).
#define STEP(i, p, vC, vL, DOSZ, CNTS)                                        \
  {                                                                           \
    if ((i) + 1 < NSTEP) WRITE_B(vC, (p) ^ 1);                                \
    if ((i) + 2 < NSTEP) {                                                    \
      LOADV_B((i) + 2, vL);                                                   \
      if (DOSZ) LOADV_S(((i) + 3) >> 1);                                      \
    }                                                                         \
    asm volatile("" ::: "memory");    /* pin B/SZ loads before stage DMAs */  \
    if ((i) + 2 < NSTEP) STAGE_A((i) + 2, rw);                                \
    const _Float16* Ab = &Alds[(ra * 2 + h) * 8192];                          \
    const _Float16* Bb = &Blds[((p) * 2 + h) * 8192];                         \
    _Pragma("unroll") for (int ks = 0; ks < 2; ++ks) {                        \
      half8 af[4], bf[4];                                                     \
      _Pragma("unroll") for (int mi = 0; mi < 4; ++mi) {                      \
        int R = wm + mi * 16 + r;                                             \
        af[mi] = *(const half8*)&Ab[R * 64 + (((ks * 4 + quad) ^ rb) << 3)];  \
      }                                                                       \
      _Pragma("unroll") for (int ni = 0; ni < 4; ++ni) {                      \
        int R = wn + ni * 16 + r;                                             \
        bf[ni] = *(const half8*)&Bb[R * 64 + (((ks * 4 + quad) ^ rb) << 3)];  \
      }                                                                       \
      _Pragma("unroll") for (int mi = 0; mi < 4; ++mi)                        \
        _Pragma("unroll") for (int ni = 0; ni < 4; ++ni)                      \
          acc[mi][ni] = __builtin_amdgcn_mfma_f32_16x16x32_f16(               \
              af[mi], bf[ni], acc[mi][ni], 0, 0, 0);                          \
    }                                                                         \
    if ((i) + 2 < NSTEP)                                                      \
      asm volatile("s_waitcnt vmcnt(" CNTS ") lgkmcnt(0)" ::: "memory");      \
    else                                                                      \
      asm volatile("s_waitcnt vmcnt(0) lgkmcnt(0)" ::: "memory");             \
    __builtin_amdgcn_s_barrier();                                             \
    __builtin_amdgcn_sched_barrier(0);                                        \
    ra = (ra + 1 == 3) ? 0 : ra + 1;                                          \
    rw = (rw + 1 == 3) ? 0 : rw + 1;                                          \
  }

  for (int i = 0; i < NSTEP; i += 2) {
    STEP(i, 0, vA, vB, 1, "12");      // even: read buf0; 12 vmem issued
    STEP(i + 1, 1, vB, vA, 0, "8");   // odd:  read buf1;  8 vmem issued
  }

  // ---- in-block split-K reduction (reuse A LDS region) ----
  floatx4* red = (floatx4*)Alds;
  if (h == 1) {
#pragma unroll
    for (int mi = 0; mi < 4; ++mi)
#pragma unroll
      for (int ni = 0; ni < 4; ++ni)
        red[(mi * 4 + ni) * 256 + w2 * 64 + lane] = acc[mi][ni];
  }
  __syncthreads();
  if (h == 0) {
#pragma unroll
    for (int mi = 0; mi < 4; ++mi) {
#pragma unroll
      for (int ni = 0; ni < 4; ++ni) {
        acc[mi][ni] += red[(mi * 4 + ni) * 256 + w2 * 64 + lane];
#pragma unroll
        for (int i = 0; i < 4; ++i) {
          int grow = bm + wm + mi * 16 + quad * 4 + i;
          int gcol = bn + wn + ni * 16 + r;
          out[(size_t)grow * N + gcol] = acc[mi][ni][i];
        }
      }
    }
  }
}

extern "C" void kernel_launch(void* const* d_in, const int* in_sizes, int n_in,
                              void* d_out, int out_size, void* d_ws, size_t ws_size,
                              hipStream_t stream) {
  const float* x = (const float*)d_in[0];
  const int* wp = (const int*)d_in[1];
  const float* wscale = (const float*)d_in[2];
  const int* wzero = (const int*)d_in[3];
  float* out = (float*)d_out;

  int M = in_sizes[0] / IN_F;  // 1024

  // Workspace: Xh (fp16 M*K = 8.39 MB) | SZ (1 MB)
  _Float16* Xh = (_Float16*)d_ws;
  uint2* SZ = (uint2*)((char*)d_ws + (size_t)M * IN_F * 2);

  int nxb = (M * IN_F / 8) / 256;       // 2048 blocks for x-convert
  int nzb = (OUT_F * NG) / 256;         // 512 blocks for scale/zero table
  prep_kernel<<<nxb + nzb, 256, 0, stream>>>(x, Xh, wscale, wzero, SZ, nxb);

  dim3 grid(OUT_F / 128, M / 128);      // (32, 8) = 256 blocks = 1/CU
  gemm_fused<<<grid, 512, 0, stream>>>(Xh, wp, SZ, out, M, OUT_F, IN_F);
}

// Round 9
// 124.154 us; speedup vs baseline: 1.6921x; 1.0131x over previous
//
#include <hip/hip_runtime.h>
#include <stdint.h>

#define IN_F 4096
#define OUT_F 4096
#define NG 32
#define NSTEP 32   // (K/2)/64 k-steps per half (in-block split-K)

typedef __attribute__((ext_vector_type(8))) _Float16 half8;
typedef __attribute__((ext_vector_type(2))) _Float16 half2t;
typedef __attribute__((ext_vector_type(4))) float floatx4;

__device__ __forceinline__ unsigned pkh(float a, float b) {
  return __builtin_bit_cast(unsigned, __builtin_amdgcn_cvt_pkrtz(a, b));
}

// ---------------------------------------------------------------------------
// Prep (R4-verified): x f32 -> fp16 pair-permuted; scale/zero -> fp16x2 table.
// ---------------------------------------------------------------------------
__global__ __launch_bounds__(256) void prep_kernel(
    const float* __restrict__ x, _Float16* __restrict__ Xh,
    const float* __restrict__ wscale, const int* __restrict__ wzero,
    uint2* __restrict__ SZ, int nxb) {
  int b = blockIdx.x;
  if (b < nxb) {
    int i = b * 256 + threadIdx.x;
    const float4* x4 = (const float4*)x;
    float4 a = x4[2 * i];
    float4 c = x4[2 * i + 1];
    uint4 o;
    o.x = pkh(a.x, c.x);   // (x0,x4)
    o.y = pkh(a.y, c.y);
    o.z = pkh(a.z, c.z);
    o.w = pkh(a.w, c.w);
    ((uint4*)Xh)[i] = o;
  } else {
    int i = (b - nxb) * 256 + threadIdx.x;
    float s = wscale[i];
    int zp = wzero[i];
    _Float16 sh = (_Float16)s;
    _Float16 ch = (_Float16)(float)(1032 + zp);  // exact in fp16
    unsigned s2 = (unsigned)__builtin_bit_cast(unsigned short, sh) * 0x10001u;
    unsigned c2 = (unsigned)__builtin_bit_cast(unsigned short, ch) * 0x10001u;
    SZ[i] = make_uint2(s2, c2);
  }
}

__device__ __forceinline__ uint4 dequant8(unsigned v, uint2 szv) {
  unsigned tx = v ^ 0x88888888u;
  half2t s2 = __builtin_bit_cast(half2t, szv.x);
  half2t c2 = __builtin_bit_cast(half2t, szv.y);
  unsigned p0 = (tx & 0x000F000Fu) | 0x64006400u;          // (n0, n4)
  unsigned p1 = ((tx >> 4) & 0x000F000Fu) | 0x64006400u;   // (n1, n5)
  unsigned p2 = ((tx >> 8) & 0x000F000Fu) | 0x64006400u;   // (n2, n6)
  unsigned p3 = ((tx >> 12) & 0x000F000Fu) | 0x64006400u;  // (n3, n7)
  half2t w0 = (__builtin_bit_cast(half2t, p0) - c2) * s2;
  half2t w1 = (__builtin_bit_cast(half2t, p1) - c2) * s2;
  half2t w2 = (__builtin_bit_cast(half2t, p2) - c2) * s2;
  half2t w3 = (__builtin_bit_cast(half2t, p3) - c2) * s2;
  uint4 o;
  o.x = __builtin_bit_cast(unsigned, w0);
  o.y = __builtin_bit_cast(unsigned, w1);
  o.z = __builtin_bit_cast(unsigned, w2);
  o.w = __builtin_bit_cast(unsigned, w3);
  return o;
}

// ---------------------------------------------------------------------------
// Fused W4A16 GEMM: R8 skeleton + 8-phase-style interleave (T3+T4+T5).
// Each K-step = 2 phases of 16 MFMA (m201 cluster size). Per phase:
//   { WRITE_B half | 8 ds_read_b128 (this ks) | 2 B-loads | 2 global_load_lds
//     -> s_barrier -> lgkmcnt(0) -> sched_barrier(0)
//     -> setprio(1) -> 16 MFMA -> setprio(0) -> s_barrier }
// Counted vmcnt once per step (phase-1 boundary): even 10, odd 8 = exactly
// this step's vmem issues (fences pin order; no other vmem in the loop) =>
// stage(i+1), issued at step i-1, is proven complete; this step's loads ride
// across. Never vmcnt(0) in the main loop. 2 waves/SIMD = m201's regime
// (m232's failed 128^2 port had only 1 wave/SIMD).
// ---------------------------------------------------------------------------
__global__ __launch_bounds__(512, 2) void gemm_fused(
    const _Float16* __restrict__ A, const int* __restrict__ wp,
    const uint2* __restrict__ SZ, float* __restrict__ out,
    int M, int N, int K) {
  __shared__ __align__(16) _Float16 Alds[6 * 8192];  // [stage][half] 96 KB
  __shared__ __align__(16) _Float16 Blds[4 * 8192];  // [buf][half]   64 KB

  const int t = threadIdx.x;
  const int wave = t >> 6, lane = t & 63;
  const int h = wave >> 2, w2 = wave & 3;
  const int wm = (w2 >> 1) * 64, wn = (w2 & 1) * 64;
  const int r = lane & 15, quad = lane >> 4, rb = r & 7;
  const int bm = blockIdx.y * 128, bn = blockIdx.x * 128;

  floatx4 acc[4][4] = {};

  // ---- A staging (R4): LDS (row,kc) holds global chunk kc^(row&7); swizzle
  // on the GLOBAL source address, LDS dest lane-linear. ----
  const int kc = t & 7, row0 = t >> 3, row1 = row0 + 64;
  const int gkc = kc ^ (row0 & 7);
  const _Float16* Ag = A + (size_t)bm * K;
  const _Float16* gA[4];
  gA[0] = Ag + (size_t)row0 * K + gkc * 8;          // half 0
  gA[1] = Ag + (size_t)row1 * K + gkc * 8;
  gA[2] = gA[0] + 2048;                             // half 1
  gA[3] = gA[1] + 2048;

#define STAGE_A_HALF(i, st, hh)                                               \
  {                                                                           \
    _Pragma("unroll") for (int j = (hh) * 2; j < (hh) * 2 + 2; ++j) {         \
      const _Float16* src = gA[j] + (i) * 64;                                 \
      int dst = ((st) * 2 + (j >> 1)) * 8192 + (t + 512 * (j & 1)) * 8;       \
      __builtin_amdgcn_global_load_lds(                                       \
          (const __attribute__((address_space(1))) void*)src,                 \
          (__attribute__((address_space(3))) void*)(&Alds[dst]), 16, 0, 0);   \
    }                                                                         \
  }

  // ---- B staging (R4): coalesced per-thread loads, swizzled ds_write. ----
  const int brow0 = t >> 3, kc8 = t & 7;
  const int* gB0 = wp + (size_t)(bn + brow0) * (IN_F / 8) + kc8;
  const int* gB1 = wp + (size_t)(bn + brow0 + 64) * (IN_F / 8) + kc8;
  const uint2* gS0 = SZ + (size_t)(bn + brow0) * NG;
  const uint2* gS1 = SZ + (size_t)(bn + brow0 + 64) * NG;
  const int bslot0 = brow0 * 64 + ((kc8 ^ (brow0 & 7)) << 3);
  const int bslot1 = (brow0 + 64) * 64 + ((kc8 ^ (brow0 & 7)) << 3);

#define LOADV_S(g)                                                            \
  {                                                                           \
    sCur[0] = gS0[(g)];                                                       \
    sCur[1] = gS1[(g)];                                                       \
    sCur[2] = gS0[(g) + 16];                                                  \
    sCur[3] = gS1[(g) + 16];                                                  \
  }

#define WRITE_B_HALF(v, dstbuf, hh)                                           \
  {                                                                           \
    _Pragma("unroll") for (int j = (hh) * 2; j < (hh) * 2 + 2; ++j) {         \
      int ofs = ((dstbuf) * 2 + (j >> 1)) * 8192 + ((j & 1) ? bslot1 : bslot0); \
      *(uint4*)&Blds[ofs] = dequant8(v[j], sCur[j]);                          \
    }                                                                         \
  }

  unsigned vA[4], vB[4];
  uint2 sCur[4];
  int ra = 0, rw = 2;   // A stage read / write indices (mod 3)

  // ---- prologue (R8-verified) ----
  {
    vB[0] = (unsigned)gB0[0];
    vB[1] = (unsigned)gB1[0];
    vB[2] = (unsigned)gB0[256];
    vB[3] = (unsigned)gB1[256];
    LOADV_S(0);
    WRITE_B_HALF(vB, 0, 0);
    WRITE_B_HALF(vB, 0, 1);             // B(0) -> buf0
    vA[0] = (unsigned)gB0[8];
    vA[1] = (unsigned)gB1[8];
    vA[2] = (unsigned)gB0[8 + 256];
    vA[3] = (unsigned)gB1[8 + 256];     // regs for step 0's WRITE_B(B1)
    asm volatile("" ::: "memory");      // pin B loads before the stage DMAs
    STAGE_A_HALF(0, 0, 0);
    STAGE_A_HALF(0, 0, 1);
    STAGE_A_HALF(1, 1, 0);
    STAGE_A_HALF(1, 1, 1);              // newest 4 vmem = stage(1)
    asm volatile("s_waitcnt vmcnt(4) lgkmcnt(0)" ::: "memory");  // A0,B0 ready
    __builtin_amdgcn_s_barrier();
    __builtin_amdgcn_sched_barrier(0);
  }

#define MFMA16(af, bf)                                                        \
  _Pragma("unroll") for (int mi = 0; mi < 4; ++mi)                            \
    _Pragma("unroll") for (int ni = 0; ni < 4; ++ni)                          \
      acc[mi][ni] = __builtin_amdgcn_mfma_f32_16x16x32_f16(                   \
          af[mi], bf[ni], acc[mi][ni], 0, 0, 0);

#define STEP(i, p, vC, vL, DOSZ, CNTS)                                        \
  {                                                                           \
    const _Float16* Ab = &Alds[(ra * 2 + h) * 8192];                          \
    const _Float16* Bb = &Blds[((p) * 2 + h) * 8192];                         \
    /* ---------------- phase 0 (ks = 0) ---------------- */                  \
    if ((i) + 1 < NSTEP) WRITE_B_HALF(vC, (p) ^ 1, 0);                        \
    half8 af0[4], bf0[4];                                                     \
    _Pragma("unroll") for (int mi = 0; mi < 4; ++mi) {                        \
      int R = wm + mi * 16 + r;                                               \
      af0[mi] = *(const half8*)&Ab[R * 64 + ((quad ^ rb) << 3)];              \
    }                                                                         \
    _Pragma("unroll") for (int ni = 0; ni < 4; ++ni) {                        \
      int R = wn + ni * 16 + r;                                               \
      bf0[ni] = *(const half8*)&Bb[R * 64 + ((quad ^ rb) << 3)];              \
    }                                                                         \
    if ((i) + 2 < NSTEP) {                                                    \
      vL[0] = (unsigned)gB0[((i) + 2) * 8];                                   \
      vL[1] = (unsigned)gB1[((i) + 2) * 8];                                   \
    }                                                                         \
    asm volatile("" ::: "memory");                                            \
    if ((i) + 2 < NSTEP) STAGE_A_HALF((i) + 2, rw, 0);                        \
    __builtin_amdgcn_s_barrier();                                             \
    asm volatile("s_waitcnt lgkmcnt(0)" ::: "memory");                        \
    __builtin_amdgcn_sched_barrier(0);                                        \
    __builtin_amdgcn_s_setprio(1);                                            \
    MFMA16(af0, bf0);                                                         \
    __builtin_amdgcn_s_setprio(0);                                            \
    __builtin_amdgcn_s_barrier();                                             \
    /* ---------------- phase 1 (ks = 1) ---------------- */                  \
    if ((i) + 1 < NSTEP) WRITE_B_HALF(vC, (p) ^ 1, 1);                        \
    half8 af1[4], bf1[4];                                                     \
    _Pragma("unroll") for (int mi = 0; mi < 4; ++mi) {                        \
      int R = wm + mi * 16 + r;                                               \
      af1[mi] = *(const half8*)&Ab[R * 64 + (((4 + quad) ^ rb) << 3)];        \
    }                                                                         \
    _Pragma("unroll") for (int ni = 0; ni < 4; ++ni) {                        \
      int R = wn + ni * 16 + r;                                               \
      bf1[ni] = *(const half8*)&Bb[R * 64 + (((4 + quad) ^ rb) << 3)];        \
    }                                                                         \
    if ((i) + 2 < NSTEP) {                                                    \
      vL[2] = (unsigned)gB0[((i) + 2) * 8 + 256];                             \
      vL[3] = (unsigned)gB1[((i) + 2) * 8 + 256];                             \
      if (DOSZ) LOADV_S(((i) + 3) >> 1);  /* after both WRITE_B halves */     \
    }                                                                         \
    asm volatile("" ::: "memory");                                            \
    if ((i) + 2 < NSTEP) STAGE_A_HALF((i) + 2, rw, 1);                        \
    if ((i) + 2 < NSTEP)                                                      \
      asm volatile("s_waitcnt vmcnt(" CNTS ")" ::: "memory");                 \
    else                                                                      \
      asm volatile("s_waitcnt vmcnt(0)" ::: "memory");                        \
    __builtin_amdgcn_s_barrier();                                             \
    asm volatile("s_waitcnt lgkmcnt(0)" ::: "memory");                        \
    __builtin_amdgcn_sched_barrier(0);                                        \
    __builtin_amdgcn_s_setprio(1);                                            \
    MFMA16(af1, bf1);                                                         \
    __builtin_amdgcn_s_setprio(0);                                            \
    __builtin_amdgcn_s_barrier();                                             \
    ra = (ra + 1 == 3) ? 0 : ra + 1;                                          \
    rw = (rw + 1 == 3) ? 0 : rw + 1;                                          \
  }

  for (int i = 0; i < NSTEP; i += 2) {
    STEP(i, 0, vA, vB, 1, "10");      // even: read buf0; 10 vmem issued
    STEP(i + 1, 1, vB, vA, 0, "8");   // odd:  read buf1;  8 vmem issued
  }

  // ---- in-block split-K reduction (reuse A LDS region) ----
  floatx4* red = (floatx4*)Alds;
  if (h == 1) {
#pragma unroll
    for (int mi = 0; mi < 4; ++mi)
#pragma unroll
      for (int ni = 0; ni < 4; ++ni)
        red[(mi * 4 + ni) * 256 + w2 * 64 + lane] = acc[mi][ni];
  }
  __syncthreads();
  if (h == 0) {
#pragma unroll
    for (int mi = 0; mi < 4; ++mi) {
#pragma unroll
      for (int ni = 0; ni < 4; ++ni) {
        acc[mi][ni] += red[(mi * 4 + ni) * 256 + w2 * 64 + lane];
#pragma unroll
        for (int i = 0; i < 4; ++i) {
          int grow = bm + wm + mi * 16 + quad * 4 + i;
          int gcol = bn + wn + ni * 16 + r;
          out[(size_t)grow * N + gcol] = acc[mi][ni][i];
        }
      }
    }
  }
}

extern "C" void kernel_launch(void* const* d_in, const int* in_sizes, int n_in,
                              void* d_out, int out_size, void* d_ws, size_t ws_size,
                              hipStream_t stream) {
  const float* x = (const float*)d_in[0];
  const int* wp = (const int*)d_in[1];
  const float* wscale = (const float*)d_in[2];
  const int* wzero = (const int*)d_in[3];
  float* out = (float*)d_out;

  int M = in_sizes[0] / IN_F;  // 1024

  // Workspace: Xh (fp16 M*K = 8.39 MB) | SZ (1 MB)
  _Float16* Xh = (_Float16*)d_ws;
  uint2* SZ = (uint2*)((char*)d_ws + (size_t)M * IN_F * 2);

  int nxb = (M * IN_F / 8) / 256;       // 2048 blocks for x-convert
  int nzb = (OUT_F * NG) / 256;         // 512 blocks for scale/zero table
  prep_kernel<<<nxb + nzb, 256, 0, stream>>>(x, Xh, wscale, wzero, SZ, nxb);

  dim3 grid(OUT_F / 128, M / 128);      // (32, 8) = 256 blocks = 1/CU
  gemm_fused<<<grid, 512, 0, stream>>>(Xh, wp, SZ, out, M, OUT_F, IN_F);
}